// Round 8
// baseline (532.642 us; speedup 1.0000x reference)
//
#include <hip/hip_runtime.h>
#include <math.h>

#define NN 50000
#define EE 400000
#define ETOT 450000      // EE + NN self loops
#define CC 64
#define HH 4
#define DEA 16
#define NBATCH 64
#define HC 256           // HH*CC
#define EPSV 1e-5f
#define NB 49            // ceil(NN/1024)
#define NPW 4            // nodes per wave in k_gat (was 8: occupancy-limited)

typedef unsigned short ushort_t;
typedef unsigned int uint_t;
typedef __attribute__((ext_vector_type(8))) short bf16x8;
typedef __attribute__((ext_vector_type(4))) float f32x4;

__device__ __forceinline__ float4 ld4(const float* p){ return *(const float4*)p; }
__device__ __forceinline__ int rfl(int v){ return __builtin_amdgcn_readfirstlane(v); }
__device__ __forceinline__ ushort_t f2b(float f){
  uint_t u = __float_as_uint(f);
  uint_t r = (u + 0x7FFFu + ((u >> 16) & 1u)) >> 16;
  return (ushort_t)r;
}
__device__ __forceinline__ float b2f_lo(uint_t u){ return __uint_as_float(u << 16); }
__device__ __forceinline__ float b2f_hi(uint_t u){ return __uint_as_float(u & 0xFFFF0000u); }

// ---------- edge_attr column sums (for self-loop mean fill) ----------
__global__ void k_easum(const float* __restrict__ ea, float* __restrict__ easum){
  int tid = threadIdx.x;
  int gid = blockIdx.x*256 + tid;
  int gsz = gridDim.x*256;              // multiple of 16 -> col stable
  float s = 0.f;
  for (long long i = gid; i < (long long)EE*DEA; i += gsz) s += ea[i];
  __shared__ float sd[256];
  sd[tid] = s; __syncthreads();
  if (tid < DEA){
    float t = 0.f;
    for (int j = tid; j < 256; j += DEA) t += sd[j];
    atomicAdd(&easum[tid], t);
  }
}

// ---------- CSR build ----------
__global__ void k_hist(const int* __restrict__ dst, int* __restrict__ cnt){
  int e = blockIdx.x*256 + threadIdx.x;
  if (e < ETOT){
    int d = (e < EE) ? dst[e] : (e - EE);
    atomicAdd(&cnt[d], 1);
  }
}

__global__ __launch_bounds__(1024)
void k_scan1(const int* __restrict__ cnt, int* __restrict__ loc, int* __restrict__ bsum){
  __shared__ int wsum[16];
  int tid = threadIdx.x, lane = tid & 63, wv = tid >> 6;
  int i = blockIdx.x*1024 + tid;
  int v = (i < NN) ? cnt[i] : 0;
  int incl = v;
  #pragma unroll
  for (int off = 1; off < 64; off <<= 1){
    int t = __shfl_up(incl, off, 64);
    if (lane >= off) incl += t;
  }
  if (lane == 63) wsum[wv] = incl;
  __syncthreads();
  if (wv == 0){
    int s = (lane < 16) ? wsum[lane] : 0;
    #pragma unroll
    for (int off = 1; off < 16; off <<= 1){
      int t = __shfl_up(s, off, 64);
      if (lane >= off) s += t;
    }
    if (lane < 16) wsum[lane] = s;
  }
  __syncthreads();
  int excl = (wv ? wsum[wv-1] : 0) + incl - v;
  if (i < NN) loc[i] = excl;
  if (tid == 1023) bsum[blockIdx.x] = wsum[15];
}

__global__ void k_scan2(int* __restrict__ bsum, int* __restrict__ row_ptr){
  int lane = threadIdx.x;   // 64 threads
  int v = (lane < NB) ? bsum[lane] : 0;
  int incl = v;
  #pragma unroll
  for (int off = 1; off < 64; off <<= 1){
    int t = __shfl_up(incl, off, 64);
    if (lane >= off) incl += t;
  }
  if (lane < NB) bsum[lane] = incl - v;
  if (lane == 63) row_ptr[NN] = incl;
}

__global__ __launch_bounds__(1024)
void k_scan3(const int* __restrict__ loc, const int* __restrict__ bsum,
             int* __restrict__ row_ptr, int* __restrict__ wp){
  int i = blockIdx.x*1024 + threadIdx.x;
  if (i < NN){
    int v = loc[i] + bsum[blockIdx.x];
    row_ptr[i] = v; wp[i] = v;
  }
}

// scatter: csrc[slot] = src node; eas[slot][16] = edge_attr (mean-filled for self loops)
__global__ void k_scatter(const int* __restrict__ dst, const int* __restrict__ src,
                          const float* __restrict__ ea, const float* __restrict__ easum,
                          int* __restrict__ wp, int* __restrict__ csrc,
                          float* __restrict__ eas){
  int e = blockIdx.x*256 + threadIdx.x;
  if (e >= ETOT) return;
  int d, s;
  if (e < EE){ d = dst[e]; s = src[e]; } else { d = e - EE; s = d; }
  int pos = atomicAdd(&wp[d], 1);
  csrc[pos] = s;
  float buf[16];
  if (e < EE){
    #pragma unroll
    for (int q = 0; q < 4; q++){
      float4 v = ld4(ea + (size_t)e*DEA + q*4);
      buf[q*4+0]=v.x; buf[q*4+1]=v.y; buf[q*4+2]=v.z; buf[q*4+3]=v.w;
    }
  } else {
    const float invE = 1.0f / (float)EE;
    #pragma unroll
    for (int k = 0; k < 16; k++) buf[k] = easum[k]*invE;
  }
  #pragma unroll
  for (int q = 0; q < 4; q++)
    *(float4*)(eas + (size_t)pos*DEA + q*4) =
      make_float4(buf[q*4+0], buf[q*4+1], buf[q*4+2], buf[q*4+3]);
}

// ---------- pack W into MFMA B-fragment-major bf16 ----------
// Wf[(layer*2+mat)][tile][kh][lane][i]: B[k][col] with col=tile*16+(lane&15),
// k = kh*32 + (lane>>4)*8 + i  (mfma_f32_16x16x32_bf16 B layout)
__global__ void k_packw(const float* __restrict__ Wl, const float* __restrict__ Wr,
                        ushort_t* __restrict__ Wf){
  int t = blockIdx.x*256 + threadIdx.x;   // 8192 threads
  if (t >= 8192) return;
  int lane  = t & 63;
  int kh    = (t >> 6) & 1;
  int tile  = (t >> 7) & 15;
  int mat   = (t >> 11) & 1;
  int layer = t >> 12;
  const float* W = (mat ? Wr : Wl) + (size_t)layer*CC*HC;
  int col = tile*16 + (lane & 15);
  int k0  = kh*32 + (lane >> 4)*8;
  uint_t pk[4];
  #pragma unroll
  for (int q = 0; q < 4; q++){
    ushort_t a = f2b(W[(size_t)(k0+2*q+0)*HC + col]);
    ushort_t b = f2b(W[(size_t)(k0+2*q+1)*HC + col]);
    pk[q] = (uint_t)a | ((uint_t)b << 16);
  }
  size_t base = (size_t)(layer*2+mat)*16384 + (size_t)(tile*2+kh)*512 + (size_t)lane*8;
  *(uint4*)(Wf + base) = make_uint4(pk[0], pk[1], pk[2], pk[3]);
}

// ---------- GraphNorm stats ----------
__global__ __launch_bounds__(256)
void k_stats(const float* __restrict__ x, const int* __restrict__ batch,
             float* __restrict__ S, float* __restrict__ Q){
  int c = threadIdx.x & 63, g = threadIdx.x >> 6;
  int r0 = blockIdx.x*256;
  int hiR = r0 + 256; if (hiR > NN) hiR = NN;
  float s = 0.f, q = 0.f;
  int curb = -1;
  for (int n = r0 + g; n < hiR; n += 4){
    int b = batch[n];
    if (b != curb){
      if (curb >= 0){ atomicAdd(&S[curb*64+c], s); atomicAdd(&Q[curb*64+c], q); }
      curb = b; s = 0.f; q = 0.f;
    }
    float v = x[(size_t)n*CC + c];
    s += v; q += v*v;
  }
  if (curb >= 0){ atomicAdd(&S[curb*64+c], s); atomicAdd(&Q[curb*64+c], q); }
}

__device__ __forceinline__ int lowerb(const int* a, int n, int key){
  int lo = 0, hi = n;
  while (lo < hi){ int mid = (lo+hi) >> 1; if (a[mid] < key) lo = mid+1; else hi = mid; }
  return lo;
}

// ---------- fold stats to per-(batch,channel) scale/shift ----------
__global__ void k_fin(const float* __restrict__ S, const float* __restrict__ Q,
                      const int* __restrict__ batch,
                      const float* __restrict__ w, const float* __restrict__ bb,
                      const float* __restrict__ ms,
                      float* __restrict__ scale, float* __restrict__ shift){
  __shared__ float cntf;
  int b = blockIdx.x, c = threadIdx.x;   // 64 x 64
  if (c == 0){
    int lo = lowerb(batch, NN, b), hi = lowerb(batch, NN, b+1);
    cntf = fmaxf((float)(hi - lo), 1.f);
  }
  __syncthreads();
  float inv = 1.f / cntf;
  float m = S[b*64+c] * inv;
  float a = ms[c] * m;
  float var = Q[b*64+c]*inv - 2.f*a*m + a*a;   // E[(x-a)^2]
  var = fmaxf(var, 0.f);
  float rstd = rsqrtf(var + EPSV);
  float sc = rstd * w[c];
  scale[b*64+c] = sc;
  shift[b*64+c] = bb[c] - a*sc;
}

// ---------- MFMA GEMM with fused GraphNorm+ReLU: [N,64] @ [64,256] -> bf16 [n][col] ----------
// 4 waves/block, wave w owns rows n0+w*16..+15. A-frag built per lane from x (no LDS).
// B-frags: 16 B coalesced loads from pre-packed Wf (L2-hot). Epilogue: LDS col-major repack.
__global__ __launch_bounds__(256)
void k_gemm(const float* __restrict__ x, const int* __restrict__ batch,
            const float* __restrict__ scale, const float* __restrict__ shift,
            const ushort_t* __restrict__ WfA, const ushort_t* __restrict__ WfB,
            ushort_t* __restrict__ outA, ushort_t* __restrict__ outB){
  const ushort_t* Wf = blockIdx.z ? WfB : WfA;
  ushort_t* out = blockIdx.z ? outB : outA;
  int n0 = blockIdx.x * 64;
  int tid = threadIdx.x, lane = tid & 63, w = tid >> 6;
  int row = n0 + w*16 + (lane & 15);
  int k0 = (lane >> 4) * 8;

  bf16x8 afr[2];
  #pragma unroll
  for (int h = 0; h < 2; h++)
    #pragma unroll
    for (int i = 0; i < 8; i++) afr[h][i] = 0;
  if (row < NN){
    int b = batch[row];
    #pragma unroll
    for (int h = 0; h < 2; h++){
      int kk = k0 + h*32;
      float4 xv0 = ld4(x + (size_t)row*CC + kk);
      float4 xv1 = ld4(x + (size_t)row*CC + kk + 4);
      float4 sc0 = ld4(scale + b*64 + kk);
      float4 sc1 = ld4(scale + b*64 + kk + 4);
      float4 sh0 = ld4(shift + b*64 + kk);
      float4 sh1 = ld4(shift + b*64 + kk + 4);
      float v[8];
      v[0]=fmaxf(xv0.x*sc0.x+sh0.x,0.f); v[1]=fmaxf(xv0.y*sc0.y+sh0.y,0.f);
      v[2]=fmaxf(xv0.z*sc0.z+sh0.z,0.f); v[3]=fmaxf(xv0.w*sc0.w+sh0.w,0.f);
      v[4]=fmaxf(xv1.x*sc1.x+sh1.x,0.f); v[5]=fmaxf(xv1.y*sc1.y+sh1.y,0.f);
      v[6]=fmaxf(xv1.z*sc1.z+sh1.z,0.f); v[7]=fmaxf(xv1.w*sc1.w+sh1.w,0.f);
      #pragma unroll
      for (int i = 0; i < 8; i++) afr[h][i] = (short)f2b(v[i]);
    }
  }

  f32x4 acc[16];
  #pragma unroll
  for (int t = 0; t < 16; t++) acc[t] = (f32x4){0.f,0.f,0.f,0.f};
  #pragma unroll 4
  for (int t = 0; t < 16; t++){
    bf16x8 b0 = *(const bf16x8*)(Wf + (size_t)(t*2+0)*512 + (size_t)lane*8);
    bf16x8 b1 = *(const bf16x8*)(Wf + (size_t)(t*2+1)*512 + (size_t)lane*8);
    acc[t] = __builtin_amdgcn_mfma_f32_16x16x32_bf16(afr[0], b0, acc[t], 0, 0, 0);
    acc[t] = __builtin_amdgcn_mfma_f32_16x16x32_bf16(afr[1], b1, acc[t], 0, 0, 0);
  }

  // epilogue: col-major LDS (stride 68 rows), then coalesced row-major global write
  __shared__ ushort_t Ct[256*68];
  int r0 = w*16 + (lane >> 4)*4;
  #pragma unroll
  for (int t = 0; t < 16; t++){
    int col = t*16 + (lane & 15);
    uint2 pk;
    pk.x = (uint_t)f2b(acc[t].x) | ((uint_t)f2b(acc[t].y) << 16);
    pk.y = (uint_t)f2b(acc[t].z) | ((uint_t)f2b(acc[t].w) << 16);
    *(uint2*)&Ct[col*68 + r0] = pk;
  }
  __syncthreads();
  int rp = 2*(tid & 31);
  int c0 = (tid >> 5) * 32;
  uint_t a[32];
  #pragma unroll
  for (int i = 0; i < 32; i++) a[i] = *(const uint_t*)&Ct[(c0+i)*68 + rp];
  uint_t o0[16], o1[16];
  #pragma unroll
  for (int j = 0; j < 16; j++){
    o0[j] = (a[2*j] & 0xFFFFu) | (a[2*j+1] << 16);
    o1[j] = (a[2*j] >> 16) | (a[2*j+1] & 0xFFFF0000u);
  }
  int nr0 = n0 + rp, nr1 = n0 + rp + 1;
  if (nr0 < NN){
    uint4* p = (uint4*)(out + (size_t)nr0*HC + c0);
    p[0] = make_uint4(o0[0],o0[1],o0[2],o0[3]);
    p[1] = make_uint4(o0[4],o0[5],o0[6],o0[7]);
    p[2] = make_uint4(o0[8],o0[9],o0[10],o0[11]);
    p[3] = make_uint4(o0[12],o0[13],o0[14],o0[15]);
  }
  if (nr1 < NN){
    uint4* p = (uint4*)(out + (size_t)nr1*HC + c0);
    p[0] = make_uint4(o1[0],o1[1],o1[2],o1[3]);
    p[1] = make_uint4(o1[4],o1[5],o1[6],o1[7]);
    p[2] = make_uint4(o1[8],o1[9],o1[10],o1[11]);
    p[3] = make_uint4(o1[12],o1[13],o1[14],o1[15]);
  }
}

// ---------- FUSED GATv2: logits + online softmax + aggregation, one CSR pass ----------
__global__ __launch_bounds__(256)
void k_gat(const int* __restrict__ row_ptr, const int* __restrict__ csrc,
           const float* __restrict__ eas,
           const ushort_t* __restrict__ xlh, const ushort_t* __restrict__ xrh,
           const float* __restrict__ We, const float* __restrict__ att,
           const float* __restrict__ bias, const float* __restrict__ resid,
           float* __restrict__ out){
  int lane = threadIdx.x & 63;
  int h = lane >> 4, cg = lane & 15;
  int col = h*64 + cg*4;
  int wid = (blockIdx.x*256 + threadIdx.x) >> 6;
  int n0 = wid * NPW;
  if (n0 >= NN) return;
  int n1 = n0 + NPW; if (n1 > NN) n1 = NN;

  float wer[4][16];
  #pragma unroll
  for (int k = 0; k < 16; k++){
    float4 w = ld4(We + (size_t)k*HC + col);
    wer[0][k]=w.x; wer[1][k]=w.y; wer[2][k]=w.z; wer[3][k]=w.w;
  }
  float4 attv = ld4(att + col);
  float4 biasv = ld4(bias + cg*4);

  for (int n = n0; n < n1; n++){
    int rr0 = rfl(row_ptr[n]), rr1 = rfl(row_ptr[n+1]);
    uint2 xrp = *(const uint2*)(xrh + (size_t)n*HC + col);
    float xr0 = b2f_lo(xrp.x), xr1 = b2f_hi(xrp.x);
    float xr2 = b2f_lo(xrp.y), xr3 = b2f_hi(xrp.y);
    float m = -3.4e38f, dsum = 0.f;
    float a0 = 0.f, a1 = 0.f, a2 = 0.f, a3 = 0.f;

    int sC = rfl(csrc[rr0]);
    uint2 xlp = *(const uint2*)(xlh + (size_t)sC*HC + col);

    for (int idx = rr0; idx < rr1; idx++){
      int idn = (idx+1 < rr1) ? idx+1 : rr0;
      int sN = rfl(csrc[idn]);
      uint2 xlq = *(const uint2*)(xlh + (size_t)sN*HC + col);

      float xl0 = b2f_lo(xlp.x), xl1 = b2f_hi(xlp.x);
      float xl2 = b2f_lo(xlp.y), xl3 = b2f_hi(xlp.y);

      const float* ep = eas + (size_t)rfl(idx)*DEA;
      float p0 = 0.f, p1 = 0.f, p2 = 0.f, p3 = 0.f;
      #pragma unroll
      for (int k = 0; k < 16; k++){
        float ek = ep[k];
        p0 += ek*wer[0][k]; p1 += ek*wer[1][k];
        p2 += ek*wer[2][k]; p3 += ek*wer[3][k];
      }
      float v0 = xl0 + xr0 + p0; v0 = (v0 > 0.f) ? v0 : 0.2f*v0;
      float v1 = xl1 + xr1 + p1; v1 = (v1 > 0.f) ? v1 : 0.2f*v1;
      float v2 = xl2 + xr2 + p2; v2 = (v2 > 0.f) ? v2 : 0.2f*v2;
      float v3 = xl3 + xr3 + p3; v3 = (v3 > 0.f) ? v3 : 0.2f*v3;
      float pl = v0*attv.x + v1*attv.y + v2*attv.z + v3*attv.w;
      #pragma unroll
      for (int off = 1; off < 16; off <<= 1) pl += __shfl_xor(pl, off, 16);

      float mn = fmaxf(m, pl);
      float sc = __expf(m - mn);
      float wexp = __expf(pl - mn);
      dsum = dsum*sc + wexp;
      a0 = a0*sc + wexp*xl0;
      a1 = a1*sc + wexp*xl1;
      a2 = a2*sc + wexp*xl2;
      a3 = a3*sc + wexp*xl3;
      m = mn;

      xlp = xlq;
    }

    float inv = 1.0f / dsum;
    float o0 = a0*inv, o1 = a1*inv, o2 = a2*inv, o3 = a3*inv;
    #pragma unroll
    for (int off = 16; off < 64; off <<= 1){
      o0 += __shfl_xor(o0, off, 64);
      o1 += __shfl_xor(o1, off, 64);
      o2 += __shfl_xor(o2, off, 64);
      o3 += __shfl_xor(o3, off, 64);
    }
    if (lane < 16){
      float r0v = o0*0.25f + biasv.x;
      float r1v = o1*0.25f + biasv.y;
      float r2v = o2*0.25f + biasv.z;
      float r3v = o3*0.25f + biasv.w;
      if (resid){
        float4 rv = ld4(resid + (size_t)n*CC + cg*4);
        r0v += rv.x; r1v += rv.y; r2v += rv.z; r3v += rv.w;
      }
      *(float4*)(out + (size_t)n*CC + cg*4) = make_float4(r0v, r1v, r2v, r3v);
    }
  }
}

extern "C" void kernel_launch(void* const* d_in, const int* in_sizes, int n_in,
                              void* d_out, int out_size, void* d_ws, size_t ws_size,
                              hipStream_t stream) {
  const float* x     = (const float*)d_in[0];
  const int*   ei    = (const int*)d_in[1];
  const int*   src   = ei;
  const int*   dst   = ei + EE;
  const float* ea    = (const float*)d_in[2];
  const int*   batch = (const int*)d_in[3];
  const float* Wl    = (const float*)d_in[4];
  const float* Wr    = (const float*)d_in[5];
  const float* We    = (const float*)d_in[6];
  const float* att   = (const float*)d_in[7];
  const float* gb    = (const float*)d_in[8];
  const float* gw    = (const float*)d_in[9];
  const float* gnb   = (const float*)d_in[10];
  const float* gms   = (const float*)d_in[11];
  float* out = (float*)d_out;

  char* ws = (char*)d_ws;
  size_t off = 0;
  auto alloc = [&](size_t bytes) -> void* {
    void* p = ws + off; off += (bytes + 255) & ~(size_t)255; return p;
  };
  int*   cnt     = (int*)alloc(NN*sizeof(int));
  int*   loc     = (int*)alloc(NN*sizeof(int));
  int*   bsum    = (int*)alloc(64*sizeof(int));
  int*   wp      = (int*)alloc(NN*sizeof(int));
  int*   row_ptr = (int*)alloc((NN+1)*sizeof(int));
  int*   csrc    = (int*)alloc((size_t)ETOT*sizeof(int));
  float* eas     = (float*)alloc((size_t)ETOT*DEA*sizeof(float));
  float* easum   = (float*)alloc(64);
  float* statSQ  = (float*)alloc(4*4096*sizeof(float));   // S[2][4096], Q[2][4096]
  float* scaleb  = (float*)alloc(4096*sizeof(float));
  float* shiftb  = (float*)alloc(4096*sizeof(float));
  ushort_t* Wf   = (ushort_t*)alloc((size_t)4*16384*sizeof(ushort_t));  // frag-major bf16
  ushort_t* xlh  = (ushort_t*)alloc((size_t)NN*HC*sizeof(ushort_t));
  ushort_t* xrh  = (ushort_t*)alloc((size_t)NN*HC*sizeof(ushort_t));
  float* xbuf    = (float*)alloc((size_t)NN*CC*sizeof(float));
  if (off > ws_size) return;   // insufficient workspace -> fail loudly (no launch)

  hipMemsetAsync(cnt, 0, NN*sizeof(int), stream);
  hipMemsetAsync(easum, 0, 64, stream);
  hipMemsetAsync(statSQ, 0, 4*4096*sizeof(float), stream);
  k_easum<<<1024, 256, 0, stream>>>(ea, easum);
  k_hist<<<(ETOT+255)/256, 256, 0, stream>>>(dst, cnt);
  k_scan1<<<NB, 1024, 0, stream>>>(cnt, loc, bsum);
  k_scan2<<<1, 64, 0, stream>>>(bsum, row_ptr);
  k_scan3<<<NB, 1024, 0, stream>>>(loc, bsum, row_ptr, wp);
  k_scatter<<<(ETOT+255)/256, 256, 0, stream>>>(dst, src, ea, easum, wp, csrc, eas);
  k_packw<<<32, 256, 0, stream>>>(Wl, Wr, Wf);

  int gatBlocks = (NN + NPW*4 - 1) / (NPW*4);
  for (int i = 0; i < 2; i++){
    const float* xin = i ? xbuf : x;
    float* S = statSQ + i*4096;
    float* Q = statSQ + 2*4096 + i*4096;
    k_stats<<<(NN+255)/256, 256, 0, stream>>>(xin, batch, S, Q);
    k_fin<<<64, 64, 0, stream>>>(S, Q, batch, gw + i*CC, gnb + i*CC, gms + i*CC, scaleb, shiftb);
    k_gemm<<<dim3((NN+63)/64, 1, 2), 256, 0, stream>>>(xin, batch, scaleb, shiftb,
                                                       Wf + (size_t)(i*2+0)*16384,
                                                       Wf + (size_t)(i*2+1)*16384,
                                                       xlh, xrh);
    k_gat<<<gatBlocks, 256, 0, stream>>>(row_ptr, csrc, eas, xlh, xrh,
                                         We + (size_t)i*DEA*HC, att + i*HH*CC,
                                         gb + i*CC, i ? x : nullptr, i ? out : xbuf);
  }
}